// Round 1
// baseline (112.743 us; speedup 1.0000x reference)
//
#include <hip/hip_runtime.h>
#include <math.h>

namespace {

constexpr int D = 32;
constexpr int KOBJ = 1023;          // objects 1..1023 (cluster id 0 = noise)
constexpr float QMIN = 0.01f;
constexpr float PTT = 0.9f;
constexpr float METAETA = 4.0f;

__device__ inline float waveSum(float v) {
#pragma unroll
  for (int o = 32; o > 0; o >>= 1) v += __shfl_down(v, o, 64);
  return v;
}

// ws accumulators: acc[0]=attSum acc[1]=repSum acc[2]=noiseSum acc[3]=noiseCnt
//                  acc[4]=hitOkCnt acc[5]=cowardSum
__global__ void k_init(float* acc, int* flagNZ, unsigned long long* keys) {
  int i = blockIdx.x * blockDim.x + threadIdx.x;
  if (i < KOBJ) keys[i] = 0ull;
  if (i < 8) acc[i] = 0.f;
  if (i == 8) flagNZ[0] = 0;
}

// cluster_ids dtype detect: if the array is int64 (values 0..1023), every odd
// 32-bit word among the first N words is 0. If int32 w/ random ids, essentially
// impossible. flagNZ=1 => int32 layout.
__global__ void k_detect(const int* __restrict__ cidw, int nwords, int* flagNZ) {
  int i = blockIdx.x * blockDim.x + threadIdx.x;
  int idx = 2 * i + 1;
  if (idx < nwords && cidw[idx] != 0) flagNZ[0] = 1;
}

__global__ void k_hits(const float* __restrict__ beta, const float* __restrict__ x,
                       const float* __restrict__ pt, const float* __restrict__ eta,
                       const int* __restrict__ recon, const int* __restrict__ cidw,
                       int N, const int* __restrict__ flagNZ,
                       float* acc, unsigned long long* keys,
                       float* __restrict__ qArr, float* __restrict__ nxArr,
                       int* __restrict__ attkArr) {
  int j = blockIdx.x * blockDim.x + threadIdx.x;
  bool valid = j < N;
  int is64 = (flagNZ[0] == 0);
  bool ok = false;
  if (valid) {
    int cid = is64 ? cidw[2 * j] : cidw[j];
    float b = beta[j];
    float bc = fminf(fmaxf(b, 0.f), 1.f - 1e-4f);
    float t = atanhf(bc);
    float q = t * t + QMIN;
    ok = (recon[j] > 0) && (pt[j] > PTT) && (fabsf(eta[j]) < METAETA);
    float nx = 0.f;
    const float4* xr = (const float4*)(x + (size_t)j * D);
#pragma unroll
    for (int i2 = 0; i2 < 8; ++i2) {
      float4 v = xr[i2];
      nx += v.x * v.x + v.y * v.y + v.z * v.z + v.w * v.w;
    }
    int attk = (ok && cid >= 1) ? cid : 0;
    qArr[j] = q;
    nxArr[j] = nx;
    attkArr[j] = attk;
    if (cid <= 0) {  // noise hit
      atomicAdd(&acc[2], b);
      atomicAdd(&acc[3], 1.f);
    }
    if (attk >= 1) {
      // argmax key: max q wins; ties -> smallest j (matches np.argmax first-max)
      unsigned long long key =
          (((unsigned long long)__float_as_uint(q)) << 32) |
          (unsigned long long)(0xFFFFFFFFu - (unsigned)j);
      atomicMax(&keys[attk - 1], key);
    }
  }
  unsigned long long bal = __ballot(ok);
  if ((threadIdx.x & 63) == 0 && bal)
    atomicAdd(&acc[4], (float)__popcll(bal));
}

__global__ void k_clusters(const float* __restrict__ beta, const float* __restrict__ x,
                           const unsigned long long* __restrict__ keys,
                           const float* __restrict__ qArr, const float* __restrict__ nxArr,
                           int* __restrict__ alphaArr, float* __restrict__ qkArr,
                           float* __restrict__ nxkArr, float* __restrict__ xkArr,
                           float* acc) {
  int k = blockIdx.x * blockDim.x + threadIdx.x;
  bool valid = k < KOBJ;
  float cw = 0.f;
  if (valid) {
    unsigned long long key = keys[k];
    int alpha = (key != 0ull) ? (int)(0xFFFFFFFFu - (unsigned)(key & 0xFFFFFFFFull)) : 0;
    alphaArr[k] = alpha;
    qkArr[k] = qArr[alpha];
    nxkArr[k] = nxArr[alpha];
    const float4* s4 = (const float4*)(x + (size_t)alpha * D);
    float4* d4 = (float4*)(xkArr + (size_t)k * D);
#pragma unroll
    for (int i = 0; i < 8; ++i) d4[i] = s4[i];
    cw = 1.f - beta[alpha];
  }
  float s = waveSum(cw);
  if ((threadIdx.x & 63) == 0 && s != 0.f) atomicAdd(&acc[5], s);
}

// exact f32 attractive term: one pair per passing hit
__global__ void k_att(const float* __restrict__ x, int N,
                      const float* __restrict__ qArr, const float* __restrict__ nxArr,
                      const int* __restrict__ attkArr, const int* __restrict__ alphaArr,
                      const float* __restrict__ qkArr, const float* __restrict__ nxkArr,
                      const float* __restrict__ xkArr, float* acc) {
  int j = blockIdx.x * blockDim.x + threadIdx.x;
  float contrib = 0.f;
  if (j < N) {
    int attk = attkArr[j];
    if (attk >= 1) {
      int k0 = attk - 1;
      const float4* xj = (const float4*)(x + (size_t)j * D);
      const float4* xk = (const float4*)(xkArr + (size_t)k0 * D);
      float dot = 0.f;
#pragma unroll
      for (int i = 0; i < 8; ++i) {
        float4 a = xj[i], b = xk[i];
        dot += a.x * b.x + a.y * b.y + a.z * b.z + a.w * b.w;
      }
      float d2 = nxArr[j] + nxkArr[k0] - 2.f * dot;
      contrib = qArr[j] * qkArr[k0] * fmaxf(d2, 1e-12f);  // dist^2 = max(d2,1e-12)
    }
  }
  float s = waveSum(contrib);
  if ((threadIdx.x & 63) == 0 && s != 0.f) atomicAdd(&acc[0], s);
}

// repulsive term: 2 hits/thread, 128-object LDS tile per block
__global__ __launch_bounds__(256) void k_pair(
    const float* __restrict__ x, int N,
    const float* __restrict__ qArr, const float* __restrict__ nxArr,
    const int* __restrict__ attkArr,
    const float* __restrict__ qkArr, const float* __restrict__ nxkArr,
    const float* __restrict__ xkArr, float* acc) {
  __shared__ float xs[128 * D];  // 16 KiB
  __shared__ float qs[128];
  __shared__ float ns[128];
  __shared__ float wsum[4];

  int t = threadIdx.x;
  int j0 = blockIdx.x * 512 + t;
  int j1 = j0 + 256;
  int kbase = blockIdx.y * 128;  // 0-based object index base
  int kid0 = kbase + 1;          // object id at kk=0

  float4 xa[8], xb[8];
  float qa = 0.f, qb = 0.f, na = 0.f, nb = 0.f;
  int aka = -1, akb = -1;
  bool va = j0 < N, vb = j1 < N;
  if (va) {
    const float4* p = (const float4*)(x + (size_t)j0 * D);
#pragma unroll
    for (int i = 0; i < 8; ++i) xa[i] = p[i];
    qa = qArr[j0]; na = nxArr[j0]; aka = attkArr[j0];
  } else {
#pragma unroll
    for (int i = 0; i < 8; ++i) xa[i] = make_float4(0.f, 0.f, 0.f, 0.f);
  }
  if (vb) {
    const float4* p = (const float4*)(x + (size_t)j1 * D);
#pragma unroll
    for (int i = 0; i < 8; ++i) xb[i] = p[i];
    qb = qArr[j1]; nb = nxArr[j1]; akb = attkArr[j1];
  } else {
#pragma unroll
    for (int i = 0; i < 8; ++i) xb[i] = make_float4(0.f, 0.f, 0.f, 0.f);
  }

  {  // stage object tile
    const float4* src = (const float4*)xkArr;
    float4* dst = (float4*)xs;
#pragma unroll
    for (int i = 0; i < 4; ++i) {
      int fi = t + i * 256;          // float4 index in tile (0..1023)
      int row = kbase + (fi >> 3);
      dst[fi] = (row < KOBJ) ? src[(size_t)kbase * 8 + fi]
                             : make_float4(0.f, 0.f, 0.f, 0.f);
    }
    if (t < 128) {
      int r = kbase + t;
      qs[t] = (r < KOBJ) ? qkArr[r] : 0.f;
      ns[t] = (r < KOBJ) ? nxkArr[r] : 3.0e38f;  // pad rows can never pass d2<1
    }
  }
  __syncthreads();

  float repA = 0.f, repB = 0.f;
#pragma unroll 2
  for (int kk = 0; kk < 128; ++kk) {
    const float4* row = (const float4*)(xs + kk * D);
    float a0 = 0.f, a1 = 0.f, a2 = 0.f, a3 = 0.f;
    float b0 = 0.f, b1 = 0.f, b2 = 0.f, b3 = 0.f;
#pragma unroll
    for (int i = 0; i < 8; ++i) {
      float4 v = row[i];
      a0 = fmaf(xa[i].x, v.x, a0);
      a1 = fmaf(xa[i].y, v.y, a1);
      a2 = fmaf(xa[i].z, v.z, a2);
      a3 = fmaf(xa[i].w, v.w, a3);
      b0 = fmaf(xb[i].x, v.x, b0);
      b1 = fmaf(xb[i].y, v.y, b1);
      b2 = fmaf(xb[i].z, v.z, b2);
      b3 = fmaf(xb[i].w, v.w, b3);
    }
    float dA = (a0 + a1) + (a2 + a3);
    float dB = (b0 + b1) + (b2 + b3);
    float nk = ns[kk];
    float d2A = na + nk - 2.f * dA;
    float d2B = nb + nk - 2.f * dB;
    int kid = kid0 + kk;
    if (va && d2A < 1.f && kid != aka)
      repA += qa * qs[kk] * (1.f - sqrtf(fmaxf(d2A, 1e-12f)));
    if (vb && d2B < 1.f && kid != akb)
      repB += qb * qs[kk] * (1.f - sqrtf(fmaxf(d2B, 1e-12f)));
  }

  float s = waveSum(repA + repB);
  if ((t & 63) == 0) wsum[t >> 6] = s;
  __syncthreads();
  if (t == 0) {
    float tot = (wsum[0] + wsum[1]) + (wsum[2] + wsum[3]);
    if (tot != 0.f) atomicAdd(&acc[1], tot);
  }
}

__global__ void k_final(const float* __restrict__ acc, int N, float* out) {
  if (threadIdx.x == 0 && blockIdx.x == 0) {
    double attSum = acc[0], repSum = acc[1], noiseSum = acc[2];
    double noiseCnt = acc[3], okCnt = acc[4], cowardSum = acc[5];
    double norm_att = 1e-9 + okCnt - (double)KOBJ;          // EPS + n_oi - n_part
    double norm_rep = 1e-9 + (double)(KOBJ - 1) * (double)N;
    double v_att = attSum / norm_att;
    double v_rep = repSum / norm_rep;
    double l_coward = cowardSum / (double)KOBJ;
    double l_noise = noiseSum / fmax(noiseCnt, 1.0);
    out[0] = (float)(v_att + 1.0 * v_rep + 0.1 * l_noise + 0.1 * l_coward);
  }
}

}  // namespace

extern "C" void kernel_launch(void* const* d_in, const int* in_sizes, int n_in,
                              void* d_out, int out_size, void* d_ws, size_t ws_size,
                              hipStream_t stream) {
  const float* beta = (const float*)d_in[0];
  const float* x = (const float*)d_in[1];
  const float* pt = (const float*)d_in[2];
  const float* eta = (const float*)d_in[3];
  const int* recon = (const int*)d_in[4];
  const int* cidw = (const int*)d_in[5];  // int32 or int64 layout, detected on device
  int N = in_sizes[0];
  float* out = (float*)d_out;

  char* w = (char*)d_ws;
  float* acc = (float*)w;                                  // 8 f32
  int* flagNZ = (int*)(w + 32);
  unsigned long long* keys = (unsigned long long*)(w + 64);  // 1023*8 = 8184 B
  int* alphaArr = (int*)(w + 8256);                          // 1023*4
  float* qkArr = (float*)(w + 12352);                        // 1023*4
  float* nxkArr = (float*)(w + 16448);                       // 1023*4
  float* xkArr = (float*)(w + 20544);                        // 1023*32*4 = 130944 B
  float* qArr = (float*)(w + 151552);                        // N*4
  float* nxArr = (float*)(w + 151552 + (size_t)N * 4);       // N*4
  int* attkArr = (int*)(w + 151552 + (size_t)N * 8);         // N*4
  // total ws use: ~751.6 KB

  int nbN = (N + 255) / 256;
  k_init<<<4, 256, 0, stream>>>(acc, flagNZ, keys);
  k_detect<<<(N / 2 + 255) / 256, 256, 0, stream>>>(cidw, N, flagNZ);
  k_hits<<<nbN, 256, 0, stream>>>(beta, x, pt, eta, recon, cidw, N, flagNZ,
                                  acc, keys, qArr, nxArr, attkArr);
  k_clusters<<<4, 256, 0, stream>>>(beta, x, keys, qArr, nxArr,
                                    alphaArr, qkArr, nxkArr, xkArr, acc);
  k_att<<<nbN, 256, 0, stream>>>(x, N, qArr, nxArr, attkArr, alphaArr,
                                 qkArr, nxkArr, xkArr, acc);
  dim3 gp((N + 511) / 512, 8);
  k_pair<<<gp, 256, 0, stream>>>(x, N, qArr, nxArr, attkArr,
                                 qkArr, nxkArr, xkArr, acc);
  k_final<<<1, 64, 0, stream>>>(acc, N, out);
}

// Round 2
// 60.404 us; speedup vs baseline: 1.8665x; 1.8665x over previous
//
#include <hip/hip_runtime.h>
#include <math.h>

namespace {

constexpr int D = 32;
constexpr int KOBJ = 1023;          // objects 1..1023 (cluster id 0 = noise)
constexpr float QMIN = 0.01f;
constexpr float PTT = 0.9f;
constexpr float METAETA = 4.0f;

typedef __attribute__((ext_vector_type(8))) short short8;
typedef __attribute__((ext_vector_type(4))) float f32x4;

__device__ inline float waveSum(float v) {
#pragma unroll
  for (int o = 32; o > 0; o >>= 1) v += __shfl_down(v, o, 64);
  return v;
}

// f32 -> bf16 round-to-nearest-even, as raw ushort bits
__device__ inline ushort f2bf(float f) {
  unsigned u = __float_as_uint(f);
  return (ushort)((u + 0x7FFFu + ((u >> 16) & 1u)) >> 16);
}

// ws accumulators: acc[0]=attSum acc[1]=repSum acc[2]=noiseSum acc[3]=noiseCnt
//                  acc[4]=hitOkCnt acc[5]=cowardSum
__global__ void k_init(float* acc, int* flagNZ, unsigned long long* keys,
                       const int* __restrict__ cidw, int N) {
  int i = blockIdx.x * blockDim.x + threadIdx.x;
  if (i < KOBJ) keys[i] = 0ull;
  if (i < 8) acc[i] = 0.f;
  if (blockIdx.x == 0) {
    if (threadIdx.x == 0) flagNZ[0] = 0;
    __syncthreads();
    // dtype detect: int64 cluster_ids (values 0..1023) => odd 32-bit words all 0.
    for (int jj = threadIdx.x; jj < 1024; jj += blockDim.x) {
      int idx = 2 * jj + 1;
      if (idx < N && cidw[idx] != 0) flagNZ[0] = 1;  // benign same-value race
    }
  }
}

__global__ void k_hits(const float* __restrict__ beta, const float* __restrict__ x,
                       const float* __restrict__ pt, const float* __restrict__ eta,
                       const int* __restrict__ recon, const int* __restrict__ cidw,
                       int N, const int* __restrict__ flagNZ,
                       float* acc, unsigned long long* keys,
                       float* __restrict__ qArr, float* __restrict__ nxArr,
                       int* __restrict__ attkArr) {
  int j = blockIdx.x * blockDim.x + threadIdx.x;
  int is64 = (flagNZ[0] == 0);
  bool ok = false;
  if (j < N) {
    int cid = is64 ? cidw[2 * j] : cidw[j];
    float b = beta[j];
    float bc = fminf(fmaxf(b, 0.f), 1.f - 1e-4f);
    float t = atanhf(bc);
    float q = t * t + QMIN;
    ok = (recon[j] > 0) && (pt[j] > PTT) && (fabsf(eta[j]) < METAETA);
    float nx = 0.f;
    const float4* xr = (const float4*)(x + (size_t)j * D);
#pragma unroll
    for (int i2 = 0; i2 < 8; ++i2) {
      float4 v = xr[i2];
      nx += v.x * v.x + v.y * v.y + v.z * v.z + v.w * v.w;
    }
    int attk = (ok && cid >= 1) ? cid : 0;
    qArr[j] = q;
    nxArr[j] = nx;
    attkArr[j] = attk;
    if (cid <= 0) {  // noise hit
      atomicAdd(&acc[2], b);
      atomicAdd(&acc[3], 1.f);
    }
    if (attk >= 1) {
      unsigned long long key =
          (((unsigned long long)__float_as_uint(q)) << 32) |
          (unsigned long long)(0xFFFFFFFFu - (unsigned)j);
      atomicMax(&keys[attk - 1], key);
    }
  }
  unsigned long long bal = __ballot(ok);
  if ((threadIdx.x & 63) == 0 && bal)
    atomicAdd(&acc[4], (float)__popcll(bal));
}

// per object: gather alpha, write qnk (q_k, nx_k) and bf16 embedding row
__global__ void k_clusters(const float* __restrict__ beta, const float* __restrict__ x,
                           const unsigned long long* __restrict__ keys,
                           const float* __restrict__ qArr, const float* __restrict__ nxArr,
                           int* __restrict__ alphaArr, float2* __restrict__ qnk,
                           ushort* __restrict__ xkb, float* acc) {
  int k = blockIdx.x * blockDim.x + threadIdx.x;
  float cw = 0.f;
  if (k < KOBJ) {
    unsigned long long key = keys[k];
    int alpha = (key != 0ull) ? (int)(0xFFFFFFFFu - (unsigned)(key & 0xFFFFFFFFull)) : 0;
    alphaArr[k] = alpha;
    qnk[k] = make_float2(qArr[alpha], nxArr[alpha]);
    const float4* s4 = (const float4*)(x + (size_t)alpha * D);
    ushort* dst = xkb + (size_t)k * D;
#pragma unroll
    for (int i = 0; i < 8; ++i) {
      float4 v = s4[i];
      dst[4 * i + 0] = f2bf(v.x);
      dst[4 * i + 1] = f2bf(v.y);
      dst[4 * i + 2] = f2bf(v.z);
      dst[4 * i + 3] = f2bf(v.w);
    }
    cw = 1.f - beta[alpha];
  } else if (k == KOBJ) {  // pad column 1023: never passes d2<1
    qnk[k] = make_float2(0.f, 1e30f);
    ushort* dst = xkb + (size_t)k * D;
#pragma unroll
    for (int i = 0; i < D; ++i) dst[i] = 0;
  }
  float s = waveSum(cw);
  if ((threadIdx.x & 63) == 0 && s != 0.f) atomicAdd(&acc[5], s);
}

// Fused kernel: blocks [0, rowgroups) do the MFMA rep sweep;
// blocks [rowgroups, rowgroups+attBlocks) do the exact-f32 att term
// (plus subtraction of attractive pairs' rep contribution).
__global__ __launch_bounds__(256) void k_pair_att(
    const float* __restrict__ x, int N, int rowgroups,
    const float* __restrict__ qArr, const float* __restrict__ nxArr,
    const int* __restrict__ attkArr, const int* __restrict__ alphaArr,
    const float2* __restrict__ qnk, const ushort* __restrict__ xkb,
    float* acc) {
  int t = threadIdx.x;

  if ((int)blockIdx.x < rowgroups) {
    // ---------------- repulsive sweep: 64 hits x 1024 objects per block -----
    __shared__ float2 qnkS[1024];
    for (int i = t; i < 1024; i += 256) qnkS[i] = qnk[i];

    int wv = t >> 6;          // wave -> object quarter
    int ln = t & 63;
    int lr = ln & 15;         // frag row/col selector
    int lk = ln >> 4;         // k-slice selector (8 elems each)
    int rowbase = blockIdx.x * 64;

    // A fragments: 4 row-tiles of 16 hits, bf16-converted in-register
    short8 afr[4];
#pragma unroll
    for (int rt = 0; rt < 4; ++rt) {
      int row = rowbase + rt * 16 + lr;
      row = min(row, N - 1);  // clamp; pad rows are disabled via ha below
      const float* p = x + (size_t)row * D + lk * 8;
      float4 v0 = *(const float4*)p;
      float4 v1 = *(const float4*)(p + 4);
      short8 a;
      a[0] = (short)f2bf(v0.x); a[1] = (short)f2bf(v0.y);
      a[2] = (short)f2bf(v0.z); a[3] = (short)f2bf(v0.w);
      a[4] = (short)f2bf(v1.x); a[5] = (short)f2bf(v1.y);
      a[6] = (short)f2bf(v1.z); a[7] = (short)f2bf(v1.w);
      afr[rt] = a;
    }
    // per-accumulator-row half-norms: ha = (|x_j|^2 - 1) / 2
    float ha[4][4];
#pragma unroll
    for (int rt = 0; rt < 4; ++rt)
#pragma unroll
      for (int i = 0; i < 4; ++i) {
        int row = rowbase + rt * 16 + lk * 4 + i;
        ha[rt][i] = (row < N) ? (nxArr[row] - 1.f) * 0.5f : 1e37f;
      }
    __syncthreads();

    float rep = 0.f;
    int objbase = wv * 256;
#pragma unroll 1
    for (int tt = 0; tt < 16; ++tt) {
      int obj = objbase + tt * 16 + lr;
      const short8 b = *(const short8*)(xkb + (size_t)obj * D + lk * 8);
      float2 qn = qnkS[obj];
      float hk = qn.y * 0.5f;
      f32x4 z = {0.f, 0.f, 0.f, 0.f};
      f32x4 dot0 = __builtin_amdgcn_mfma_f32_16x16x32_bf16(afr[0], b, z, 0, 0, 0);
      f32x4 dot1 = __builtin_amdgcn_mfma_f32_16x16x32_bf16(afr[1], b, z, 0, 0, 0);
      f32x4 dot2 = __builtin_amdgcn_mfma_f32_16x16x32_bf16(afr[2], b, z, 0, 0, 0);
      f32x4 dot3 = __builtin_amdgcn_mfma_f32_16x16x32_bf16(afr[3], b, z, 0, 0, 0);
      // d2 < 1  <=>  dot > ha + nk/2
      float m = -1e30f;
#pragma unroll
      for (int i = 0; i < 4; ++i) {
        m = fmaxf(m, dot0[i] - (ha[0][i] + hk));
        m = fmaxf(m, dot1[i] - (ha[1][i] + hk));
        m = fmaxf(m, dot2[i] - (ha[2][i] + hk));
        m = fmaxf(m, dot3[i] - (ha[3][i] + hk));
      }
      if (__any(m > 0.f)) {  // rare: some pair within unit distance
        float qk = qn.x;
        float nk1 = qn.y + 1.f;
#pragma unroll
        for (int rt = 0; rt < 4; ++rt) {
          float d0 = (rt == 0) ? dot0[0] : (rt == 1) ? dot1[0] : (rt == 2) ? dot2[0] : dot3[0];
          float d1 = (rt == 0) ? dot0[1] : (rt == 1) ? dot1[1] : (rt == 2) ? dot2[1] : dot3[1];
          float d2v = (rt == 0) ? dot0[2] : (rt == 1) ? dot1[2] : (rt == 2) ? dot2[2] : dot3[2];
          float d3 = (rt == 0) ? dot0[3] : (rt == 1) ? dot1[3] : (rt == 2) ? dot2[3] : dot3[3];
          float dd[4] = {d0, d1, d2v, d3};
#pragma unroll
          for (int i = 0; i < 4; ++i) {
            float d2 = fmaf(2.f, ha[rt][i] - dd[i], nk1);
            if (d2 < 1.f) {
              int row = rowbase + rt * 16 + lk * 4 + i;
              rep += qArr[row] * qk * (1.f - sqrtf(fmaxf(d2, 1e-12f)));
            }
          }
        }
      }
    }
    float s = waveSum(rep);
    if ((t & 63) == 0 && s != 0.f) atomicAdd(&acc[1], s);
  } else {
    // ---------------- exact f32 attractive term + rep subtraction ----------
    int j = (blockIdx.x - rowgroups) * 256 + t;
    float attc = 0.f, repSub = 0.f;
    if (j < N) {
      int attk = attkArr[j];
      if (attk >= 1) {
        int k0 = attk - 1;
        int alpha = alphaArr[k0];
        float2 qn = qnk[k0];  // (q_k, nx_k) exact f32
        const float4* xj = (const float4*)(x + (size_t)j * D);
        const float4* xk = (const float4*)(x + (size_t)alpha * D);
        float dot = 0.f;
#pragma unroll
        for (int i = 0; i < 8; ++i) {
          float4 a = xj[i], b = xk[i];
          dot += a.x * b.x + a.y * b.y + a.z * b.z + a.w * b.w;
        }
        float d2 = nxArr[j] + qn.y - 2.f * dot;
        float w = qArr[j] * qn.x;
        attc = w * fmaxf(d2, 1e-12f);
        if (d2 < 1.f)  // this att pair was counted by the rep sweep: subtract
          repSub = w * (1.f - sqrtf(fmaxf(d2, 1e-12f)));
      }
    }
    float sa = waveSum(attc);
    float sr = waveSum(repSub);
    if ((t & 63) == 0) {
      if (sa != 0.f) atomicAdd(&acc[0], sa);
      if (sr != 0.f) atomicAdd(&acc[1], -sr);
    }
  }
}

__global__ void k_final(const float* __restrict__ acc, int N, float* out) {
  if (threadIdx.x == 0 && blockIdx.x == 0) {
    double attSum = acc[0], repSum = acc[1], noiseSum = acc[2];
    double noiseCnt = acc[3], okCnt = acc[4], cowardSum = acc[5];
    double norm_att = 1e-9 + okCnt - (double)KOBJ;
    double norm_rep = 1e-9 + (double)(KOBJ - 1) * (double)N;
    double v_att = attSum / norm_att;
    double v_rep = repSum / norm_rep;
    double l_coward = cowardSum / (double)KOBJ;
    double l_noise = noiseSum / fmax(noiseCnt, 1.0);
    out[0] = (float)(v_att + 1.0 * v_rep + 0.1 * l_noise + 0.1 * l_coward);
  }
}

}  // namespace

extern "C" void kernel_launch(void* const* d_in, const int* in_sizes, int n_in,
                              void* d_out, int out_size, void* d_ws, size_t ws_size,
                              hipStream_t stream) {
  const float* beta = (const float*)d_in[0];
  const float* x = (const float*)d_in[1];
  const float* pt = (const float*)d_in[2];
  const float* eta = (const float*)d_in[3];
  const int* recon = (const int*)d_in[4];
  const int* cidw = (const int*)d_in[5];  // int32 or int64 layout, device-detected
  int N = in_sizes[0];
  float* out = (float*)d_out;

  char* w = (char*)d_ws;
  float* acc = (float*)w;                                   // 8 f32
  int* flagNZ = (int*)(w + 32);
  unsigned long long* keys = (unsigned long long*)(w + 64); // 1023*8
  int* alphaArr = (int*)(w + 8256);                         // 1023*4
  float2* qnk = (float2*)(w + 12352);                       // 1024*8
  ushort* xkb = (ushort*)(w + 20544);                       // 1024*32*2 = 65536
  float* qArr = (float*)(w + 86080);                        // N*4
  float* nxArr = (float*)(w + 86080 + (size_t)N * 4);       // N*4
  int* attkArr = (int*)(w + 86080 + (size_t)N * 8);         // N*4
  // total ws use ~686 KB

  int nbN = (N + 255) / 256;
  int rowgroups = (N + 63) / 64;

  k_init<<<4, 256, 0, stream>>>(acc, flagNZ, keys, cidw, N);
  k_hits<<<nbN, 256, 0, stream>>>(beta, x, pt, eta, recon, cidw, N, flagNZ,
                                  acc, keys, qArr, nxArr, attkArr);
  k_clusters<<<4, 256, 0, stream>>>(beta, x, keys, qArr, nxArr,
                                    alphaArr, qnk, xkb, acc);
  k_pair_att<<<rowgroups + nbN, 256, 0, stream>>>(x, N, rowgroups, qArr, nxArr,
                                                  attkArr, alphaArr, qnk, xkb, acc);
  k_final<<<1, 64, 0, stream>>>(acc, N, out);
}